// Round 1
// baseline (303.075 us; speedup 1.0000x reference)
//
#include <hip/hip_runtime.h>
#include <hip/hip_bf16.h>
#include <stdint.h>

#define ENC_DIM 2048
#define ATT_DIM 512
#define BATCH   256
#define NPIX    196
#define MTOT    (BATCH*NPIX)          // 50176
#define CTX_OFF (BATCH*ENC_DIM)       // 524288 floats: context, then alpha

typedef __attribute__((ext_vector_type(8))) short  short8;
typedef __attribute__((ext_vector_type(4))) float  f32x4;

__device__ __forceinline__ unsigned short f2bf(float x) {
    union { float f; uint32_t u; } v; v.f = x;
    return (unsigned short)((v.u + 0x7FFFu + ((v.u >> 16) & 1u)) >> 16);
}

// ---------------------------------------------------------------------------
// Kernel 0: pack W_enc (fp32 [2048][512]) -> bf16 fragment-native layout
// Wp[(k/8)*512 + n][8] : 8 consecutive k per 16B slot (MFMA B-operand order)
// ---------------------------------------------------------------------------
__global__ __launch_bounds__(256) void pack_wenc(const float* __restrict__ W,
                                                 unsigned short* __restrict__ Wp) {
    const int i  = blockIdx.x * 256 + threadIdx.x;   // 0 .. 131071
    const int n  = i & 511;
    const int kg = i >> 9;                            // 0 .. 255
    short8 v;
#pragma unroll
    for (int j = 0; j < 8; ++j)
        v[j] = (short)f2bf(W[(size_t)(kg * 8 + j) * 512 + n]);
    *(short8*)(Wp + (size_t)i * 8) = v;
}

// ---------------------------------------------------------------------------
// Kernel 1: att2p[b][a] = hidden[b,:] @ W_dec[:,a] + b_dec[a] + b_enc[a]
// ---------------------------------------------------------------------------
__global__ __launch_bounds__(256) void att2_kernel(const float* __restrict__ hidden,
                                                   const float* __restrict__ Wdec,
                                                   const float* __restrict__ bdec,
                                                   const float* __restrict__ benc,
                                                   float* __restrict__ att2p) {
    __shared__ float h[512];
    const int b   = blockIdx.x;
    const int tid = threadIdx.x;
    h[tid]       = hidden[(size_t)b * 512 + tid];
    h[tid + 256] = hidden[(size_t)b * 512 + tid + 256];
    __syncthreads();
    float acc0 = bdec[tid]       + benc[tid];
    float acc1 = bdec[tid + 256] + benc[tid + 256];
#pragma unroll 4
    for (int k = 0; k < 512; ++k) {
        const float hk = h[k];
        acc0 = fmaf(hk, Wdec[(size_t)k * 512 + tid],       acc0);
        acc1 = fmaf(hk, Wdec[(size_t)k * 512 + tid + 256], acc1);
    }
    att2p[(size_t)b * 512 + tid]       = acc0;
    att2p[(size_t)b * 512 + tid + 256] = acc1;
}

// ---------------------------------------------------------------------------
// Kernel 2: scores[m] = sum_a relu( (enc[m,:] @ W_enc)[a] + att2p[b(m),a] ) * Wf[a]
// Block: 512 threads = 8 waves. BM=64 rows, all 512 cols (wave w owns cols
// [64w, 64w+64)). KC=64 K-chunk, single-buffered LDS. MFMA 16x16x32 bf16.
// ---------------------------------------------------------------------------
__global__ __launch_bounds__(512) void score_kernel(const float* __restrict__ enc,
                                                    const unsigned short* __restrict__ Wp,
                                                    const float* __restrict__ att2p,
                                                    const float* __restrict__ Wfull,
                                                    float* __restrict__ scores) {
    __shared__ __align__(16) unsigned short ldsA[64 * 64];      // 8 KB, swizzled
    __shared__ __align__(16) unsigned short ldsB[8 * 512 * 8];  // 64 KB [kg][col][8]
    __shared__ float lds_att2[2][ATT_DIM];                      // 4 KB
    __shared__ float lds_wf[ATT_DIM];                           // 2 KB
    __shared__ float lds_sc[64];                                // 256 B

    const int tid = threadIdx.x;
    const int w   = tid >> 6;        // wave 0..7
    const int l   = tid & 63;        // lane
    const int m0  = blockIdx.x * 64;
    const int b0  = m0 / NPIX;
    const int b1  = (m0 + 63) / NPIX;

    lds_att2[0][tid] = att2p[(size_t)b0 * ATT_DIM + tid];
    lds_att2[1][tid] = att2p[(size_t)b1 * ATT_DIM + tid];
    if (tid < ATT_DIM - 512 + 512) lds_wf[tid] = Wfull[tid];    // tid<512 always
    if (tid < 64) lds_sc[tid] = 0.0f;

    f32x4 acc[4][4];
#pragma unroll
    for (int i = 0; i < 4; ++i)
#pragma unroll
        for (int j = 0; j < 4; ++j)
            acc[i][j] = (f32x4){0.f, 0.f, 0.f, 0.f};

    // A staging geometry: thread -> (row, 8-k slot), swizzled slot for LDS
    const int ar      = tid >> 3;                       // 0..63
    const int akk     = (tid & 7) << 3;                 // 0,8,..,56
    const int aslot   = (tid & 7) ^ (ar & 7);           // XOR swizzle
    unsigned short* aw = ldsA + ar * 64 + aslot * 8;
    const float* abase = enc + (size_t)(m0 + ar) * ENC_DIM + akk;

    const short8* bsrc = (const short8*)Wp;
    short8*       bdst = (short8*)ldsB;

    for (int kc = 0; kc < ENC_DIM; kc += 64) {
        // ---- stage A chunk: 64 rows x 64 k, fp32 -> bf16 ----
        f32x4 f0 = *(const f32x4*)(abase + kc);
        f32x4 f1 = *(const f32x4*)(abase + kc + 4);
        short8 av;
        av[0] = (short)f2bf(f0[0]); av[1] = (short)f2bf(f0[1]);
        av[2] = (short)f2bf(f0[2]); av[3] = (short)f2bf(f0[3]);
        av[4] = (short)f2bf(f1[0]); av[5] = (short)f2bf(f1[1]);
        av[6] = (short)f2bf(f1[2]); av[7] = (short)f2bf(f1[3]);
        *(short8*)aw = av;
        // ---- stage B chunk: 64 k x 512 cols bf16 (contiguous 64 KB) ----
        const short8* bs = bsrc + (size_t)kc * 64;
#pragma unroll
        for (int it = 0; it < 8; ++it)
            bdst[it * 512 + tid] = bs[it * 512 + tid];
        __syncthreads();
        // ---- compute: 2 k32-steps x (4 A-frags, 4 B-frags, 16 MFMA) ----
#pragma unroll
        for (int ks = 0; ks < 2; ++ks) {
            const int kg = ks * 4 + (l >> 4);
            short8 af[4], bfv[4];
#pragma unroll
            for (int mf = 0; mf < 4; ++mf) {
                const int r = mf * 16 + (l & 15);
                af[mf] = *(const short8*)(ldsA + r * 64 + ((kg ^ (r & 7)) * 8));
            }
#pragma unroll
            for (int nf = 0; nf < 4; ++nf) {
                const int col = w * 64 + nf * 16 + (l & 15);
                bfv[nf] = *(const short8*)(ldsB + ((size_t)kg * 512 + col) * 8);
            }
#pragma unroll
            for (int mf = 0; mf < 4; ++mf)
#pragma unroll
                for (int nf = 0; nf < 4; ++nf)
                    acc[mf][nf] = __builtin_amdgcn_mfma_f32_16x16x32_bf16(
                        af[mf], bfv[nf], acc[mf][nf], 0, 0, 0);
        }
        __syncthreads();
    }

    // ---- epilogue: bias + relu + dot(Wf), reduce to per-row scores ----
#pragma unroll
    for (int mf = 0; mf < 4; ++mf) {
#pragma unroll
        for (int reg = 0; reg < 4; ++reg) {
            const int row = mf * 16 + ((l >> 4) << 2) + reg;
            const int sel = ((m0 + row) >= (b0 + 1) * NPIX) ? 1 : 0;
            float sv = 0.0f;
#pragma unroll
            for (int nf = 0; nf < 4; ++nf) {
                const int col = (w << 6) + (nf << 4) + (l & 15);
                float v = acc[mf][nf][reg] + lds_att2[sel][col];
                v = fmaxf(v, 0.0f);
                sv = fmaf(v, lds_wf[col], sv);
            }
            sv += __shfl_xor(sv, 8);
            sv += __shfl_xor(sv, 4);
            sv += __shfl_xor(sv, 2);
            sv += __shfl_xor(sv, 1);
            if ((l & 15) == 0) atomicAdd(&lds_sc[row], sv);
        }
    }
    __syncthreads();
    if (tid < 64) scores[m0 + tid] = lds_sc[tid];
}

// ---------------------------------------------------------------------------
// Kernel 3: softmax over pixels + context = enc^T @ alpha
// grid = 512 blocks: (b, e-half). Each block: softmax (redundant per half),
// then streams enc[b, :, eh*1024 : +1024].
// ---------------------------------------------------------------------------
__global__ __launch_bounds__(256) void ctx_kernel(const float* __restrict__ enc,
                                                  const float* __restrict__ scores,
                                                  float* __restrict__ out) {
    __shared__ float salpha[NPIX];
    __shared__ float red[8];
    const int tid  = threadIdx.x;
    const int lane = tid & 63;
    const int wid  = tid >> 6;
    const int b    = blockIdx.x >> 1;
    const int eh   = blockIdx.x & 1;

    const float sv = (tid < NPIX) ? scores[(size_t)b * NPIX + tid] : -1e30f;
    float mx = sv;
#pragma unroll
    for (int m = 32; m >= 1; m >>= 1) mx = fmaxf(mx, __shfl_xor(mx, m));
    if (lane == 0) red[wid] = mx;
    __syncthreads();
    if (tid == 0) red[4] = fmaxf(fmaxf(red[0], red[1]), fmaxf(red[2], red[3]));
    __syncthreads();
    const float bm = red[4];
    const float ex = (tid < NPIX) ? __expf(sv - bm) : 0.0f;
    float sm = ex;
#pragma unroll
    for (int m = 32; m >= 1; m >>= 1) sm += __shfl_xor(sm, m);
    if (lane == 0) red[wid] = sm;
    __syncthreads();
    if (tid == 0) red[5] = red[0] + red[1] + red[2] + red[3];
    __syncthreads();
    const float inv = 1.0f / red[5];
    const float av  = ex * inv;
    if (tid < NPIX) {
        salpha[tid] = av;
        if (eh == 0) out[CTX_OFF + (size_t)b * NPIX + tid] = av;
    }
    __syncthreads();

    const float* ep = enc + (size_t)b * NPIX * ENC_DIM + eh * 1024 + tid;
    float a0 = 0.f, a1 = 0.f, a2 = 0.f, a3 = 0.f;
#pragma unroll 2
    for (int n = 0; n < NPIX; ++n) {
        const float al = salpha[n];
        const float* p = ep + (size_t)n * ENC_DIM;
        a0 = fmaf(al, p[0],   a0);
        a1 = fmaf(al, p[256], a1);
        a2 = fmaf(al, p[512], a2);
        a3 = fmaf(al, p[768], a3);
    }
    float* cp = out + (size_t)b * 2048 + eh * 1024 + tid;
    cp[0]   = a0;
    cp[256] = a1;
    cp[512] = a2;
    cp[768] = a3;
}

// ---------------------------------------------------------------------------
extern "C" void kernel_launch(void* const* d_in, const int* in_sizes, int n_in,
                              void* d_out, int out_size, void* d_ws, size_t ws_size,
                              hipStream_t stream) {
    const float* enc    = (const float*)d_in[0];   // [256,196,2048]
    const float* hidden = (const float*)d_in[1];   // [256,512]
    const float* Wenc   = (const float*)d_in[2];   // [2048,512]
    const float* benc   = (const float*)d_in[3];   // [512]
    const float* Wdec   = (const float*)d_in[4];   // [512,512]
    const float* bdec   = (const float*)d_in[5];   // [512]
    const float* Wfull  = (const float*)d_in[6];   // [512,1] -> flat [512]
    // d_in[7] = b_full: softmax-shift-invariant, unused.
    float* out = (float*)d_out;

    unsigned short* Wp    = (unsigned short*)d_ws;                       // 2 MB
    float*          att2p = (float*)((char*)d_ws + (2u << 20));          // 512 KB
    float*          scores= (float*)((char*)d_ws + (2u << 20) + (512u << 10)); // 200 KB

    pack_wenc  <<<512, 256, 0, stream>>>(Wenc, Wp);
    att2_kernel<<<BATCH, 256, 0, stream>>>(hidden, Wdec, bdec, benc, att2p);
    score_kernel<<<MTOT / 64, 512, 0, stream>>>(enc, Wp, att2p, Wfull, scores);
    ctx_kernel <<<BATCH * 2, 256, 0, stream>>>(enc, scores, out);
}